// Round 7
// baseline (150.624 us; speedup 1.0000x reference)
//
#include <hip/hip_runtime.h>
#include <hip/hip_fp16.h>
#include <hip/hip_fp8.h>
#include <stdint.h>

typedef _Float16 f16;
typedef _Float16 half8 __attribute__((ext_vector_type(8)));
typedef _Float16 half4v __attribute__((ext_vector_type(4)));
typedef float floatx4 __attribute__((ext_vector_type(4)));
typedef long long i64;
typedef long long i64x2 __attribute__((ext_vector_type(2)));

#define NCAM 6
#define NPIX 16896          // 6*32*88
#define CIN 256
#define OUT1_OFF 2230272    // geom elements before 'out'

// workspace byte offsets
#define AB_OFF     4096
#define W3P_OFF    16384
#define W1P_OFF    163840
#define W2P_OFF    1343488
#define XPAD_OFF   2523136
#define Y1P_OFF    11923456
#define XPAD8_BYTES 4700160  // 6*34*90*256 fp8
#define Y1P8_OFF   (XPAD_OFF + XPAD8_BYTES)

// counted-vmcnt pipeline barriers. Single asm block so no memory op can be
// scheduled between the wait and the barrier.
#define PIPE_BAR6()  asm volatile("s_waitcnt vmcnt(6) lgkmcnt(0)\n\ts_barrier" ::: "memory")
#define PIPE_BAR0()  asm volatile("s_waitcnt vmcnt(0) lgkmcnt(0)\n\ts_barrier" ::: "memory")
// WAR barrier before re-staging a buffer: drain own LDS reads, no vmcnt drain.
#define PIPE_BARL()  asm volatile("s_waitcnt lgkmcnt(0)\n\ts_barrier" ::: "memory")

// ---------------- async global->LDS ----------------
__device__ __forceinline__ void gld16(const void* gsrc, void* ldst) {
    typedef __attribute__((address_space(1))) const uint32_t GBuf;
    typedef __attribute__((address_space(3))) uint32_t LBuf;
    __builtin_amdgcn_global_load_lds((GBuf*)(uintptr_t)gsrc,
                                     (LBuf*)(uint32_t)(uintptr_t)ldst,
                                     16, 0, 0);
}

__device__ __forceinline__ uint8_t f2fp8(float v) {
    __hip_fp8_e4m3 q(v);
    return (uint8_t)q.__x;
}

// fp8 channel permutation within a 128-block (so one 16B LDS slot holds the
// two 8B K-fragments kk=2P and kk=2P+1 of one kslot):
// c128 = (2P+kh)*32 + ks*8 + jj  ->  pos128 = (P*4+ks)*16 + kh*8 + jj
__device__ __forceinline__ int fp8pos(int c) {
    int c128 = c & 127;
    int P  = c128 >> 6;
    int kh = (c128 >> 5) & 1;
    int ks = (c128 >> 3) & 3;
    return (c >> 7) * 128 + (P * 4 + ks) * 16 + kh * 8 + (c & 7);
}

// ---------------- 3x3 inverse ----------------
__device__ __forceinline__ void inv3(const float* m, float* o) {
    float a=m[0],b=m[1],c=m[2],d=m[3],e=m[4],f=m[5],g=m[6],h=m[7],i=m[8];
    float A  =  (e*i - f*h);
    float Bc = -(d*i - f*g);
    float Cc =  (d*h - e*g);
    float det = a*A + b*Bc + c*Cc;
    float r = 1.0f/det;
    o[0]=A*r;   o[1]=-(b*i - c*h)*r; o[2]= (b*f - c*e)*r;
    o[3]=Bc*r;  o[4]= (a*i - c*g)*r; o[5]=-(a*f - c*d)*r;
    o[6]=Cc*r;  o[7]=-(a*h - b*g)*r; o[8]= (a*e - b*d)*r;
}

// geom for one flat index, matrices recomputed (cheap, broadcast loads)
__device__ __forceinline__ void geom_point(int idx,
        const float* __restrict__ rot, const float* __restrict__ trans,
        const float* __restrict__ K, const float* __restrict__ prot,
        const float* __restrict__ ptrans, float* __restrict__ out) {
    int w = idx % 88;
    int h = (idx / 88) % 32;
    int d = (idx / 2816) % 44;
    int n = idx / 123904;
    float P[9], Km[9], R[9], iP[9], iK[9], C[9];
    #pragma unroll
    for (int i = 0; i < 9; ++i) { P[i]=prot[n*9+i]; Km[i]=K[n*9+i]; R[i]=rot[n*9+i]; }
    inv3(P, iP);
    inv3(Km, iK);
    #pragma unroll
    for (int i = 0; i < 3; ++i)
        #pragma unroll
        for (int j = 0; j < 3; ++j)
            C[i*3+j] = R[i*3+0]*iK[0*3+j] + R[i*3+1]*iK[1*3+j] + R[i*3+2]*iK[2*3+j];
    float fx = w * (703.0f / 87.0f);
    float fy = h * (255.0f / 31.0f);
    float fz = d + 1.0f;
    float px = fx - ptrans[n*3+0], py = fy - ptrans[n*3+1], pz = fz - ptrans[n*3+2];
    float q0 = iP[0]*px + iP[1]*py + iP[2]*pz;
    float q1 = iP[3]*px + iP[4]*py + iP[5]*pz;
    float q2 = iP[6]*px + iP[7]*py + iP[8]*pz;
    float r0 = q0 * q2, r1 = q1 * q2, r2 = q2;
    out[idx*3 + 0] = C[0]*r0 + C[1]*r1 + C[2]*r2 + trans[n*3+0];
    out[idx*3 + 1] = C[3]*r0 + C[4]*r1 + C[5]*r2 + trans[n*3+1];
    out[idx*3 + 2] = C[6]*r0 + C[7]*r1 + C[8]*r2 + trans[n*3+2];
}

// ---------------- fused prep: border-zero + wperm + xpad + ab ----------------
// blocks 0..11      : zero fp8 pad borders of xpad8 (0..5) and y1p8 (6..11)
// blocks 12..715    : weight permute->fp8 (oc = bid-12; 512 for w1/w2) / w3p f16 (last 192)
// blocks 716..1483  : NCHW->NHWC-fp8 transpose of feats (one (n,h,icg) per block)
// block  1484       : folded BN coeffs (w-scale 1/16 folded) + padded b3
// (geom moved to the splat launch tail - off the prep->conv1 critical path)
__global__ __launch_bounds__(256) void fused_prep(
        const float* __restrict__ feats,
        const float* __restrict__ w1, const float* __restrict__ w2,
        const float* __restrict__ w3,
        const float* __restrict__ b1, const float* __restrict__ g1,
        const float* __restrict__ be1, const float* __restrict__ m1, const float* __restrict__ v1,
        const float* __restrict__ b2, const float* __restrict__ g2,
        const float* __restrict__ be2, const float* __restrict__ m2, const float* __restrict__ v2,
        const float* __restrict__ b3,
        uint8_t* __restrict__ w1p, uint8_t* __restrict__ w2p, f16* __restrict__ w3p,
        float* __restrict__ ab, uint8_t* __restrict__ xpad8, uint8_t* __restrict__ y1p8) {
    int bid = blockIdx.x;
    int t = threadIdx.x;
    if (bid < 12) {
        // zero only the pad border (interior written by transpose / conv epilogues)
        uint8_t* buf = (bid < 6) ? xpad8 : y1p8;
        int n = bid % 6;
        for (int i = t; i < 3904; i += 256) {      // 244 border pixels * 16 uint4
            int u = i >> 4, c = i & 15;
            int h, w;
            if (u < 90)       { h = 0;       w = u; }
            else if (u < 180) { h = 33;      w = u - 90; }
            else if (u < 212) { h = u - 179; w = 0; }
            else              { h = u - 211; w = 89; }
            *(uint4*)&buf[((size_t)((n*34 + h)*90 + w))*256 + c*16] = uint4{0,0,0,0};
        }
        return;
    }
    if (bid < 716) {
        int oc = bid - 12;                     // 0..703
        if (oc < 512) {
            // fp8 weight, x16 scaled, laid out [oc][win(18)][slot(8)][16B]
            const float* s = ((oc < 256) ? w1 : w2) + (size_t)(oc & 255) * 2304;
            uint8_t* dst = ((oc < 256) ? w1p : w2p) + (size_t)(oc & 255) * 2304;
            for (int idx = t; idx < 2304; idx += 256) {
                int win = idx >> 7, b = idx & 127;
                int sl = b >> 4, j = b & 15;
                int P = sl >> 2, ks = sl & 3, kh = j >> 3, jj = j & 7;
                int kwin = (2*P + kh)*32 + ks*8 + jj;
                int Kg = win*128 + kwin;
                int tap = Kg >> 8, c = Kg & 255;
                dst[idx] = f2fp8(s[c*9 + tap] * 16.0f);
            }
        } else {
            int r = oc - 512;                  // 0..191
            w3p[r * 256 + t] = (r < 130) ? (f16)w3[r * 256 + t] : (f16)0.0f;
        }
        return;
    }
    if (bid < 1484) {
        __shared__ float tile[64][89];
        int b = bid - 716;                     // 0..767 : (n, h, icg)
        int n = b >> 7;
        int h = (b >> 2) & 31;
        int icg = b & 3;
        int ic0 = icg * 64;
        #pragma unroll
        for (int j = 0; j < 22; ++j) {
            int idx = j * 256 + t;
            int r = idx / 88, w = idx - r * 88;
            tile[r][w] = feats[((size_t)(n*256 + ic0 + r) * 32 + h) * 88 + w];
        }
        __syncthreads();
        // write 88 px * 16 channel-quads as fp8 with fp8pos permutation
        for (int j = 0; j < 6; ++j) {
            int idx = j * 256 + t;
            if (idx < 1408) {
                int w = idx >> 4, cq = idx & 15;
                int c = cq * 4;
                int ca = ic0 + c;
                uint32_t u = (uint32_t)f2fp8(tile[c][w])
                           | ((uint32_t)f2fp8(tile[c+1][w]) << 8)
                           | ((uint32_t)f2fp8(tile[c+2][w]) << 16)
                           | ((uint32_t)f2fp8(tile[c+3][w]) << 24);
                size_t px = (size_t)((n*34 + h + 1) * 90 + (w + 1));
                *(uint32_t*)&xpad8[px*256 + fp8pos(ca)] = u;
            }
        }
        return;
    }
    // bid == 1484
    {
        float a1 = g1[t] * rsqrtf(v1[t] + 1e-3f);
        ab[t]       = a1 * 0.0625f;            // fold 1/16 weight scale
        ab[256 + t] = (b1[t] - m1[t]) * a1 + be1[t];
        float a2 = g2[t] * rsqrtf(v2[t] + 1e-3f);
        ab[512 + t] = a2 * 0.0625f;
        ab[768 + t] = (b2[t] - m2[t]) * a2 + be2[t];
        if (t < 192) ab[1024 + t] = (t < 130) ? b3[t] : 0.0f;
    }
}

// ---------------- conv 3x3 implicit GEMM, fp8 MFMA ----------------
// 256 threads / 4 waves, wave tile 32oc x 64px, double-buffered LDS,
// BAR6/BARL split barriers, setprio, XCD swizzle. fp8 e4m3: K-window = 128
// (18 windows), LDS rows 128B / 8 slots of 16B, XOR swizzle (conflict-free).
template<bool FP8OUT>
__global__ __launch_bounds__(256, 3) void conv8_mfma(
        const uint8_t* __restrict__ xin,  // fp8 padded NHWC-perm [6][34][90][256]
        const uint8_t* __restrict__ wp,   // fp8 [256][18][8][16]
        const float* __restrict__ ab, int abOff,
        uint8_t* __restrict__ yout8,      // fp8 out (conv1)
        f16* __restrict__ yout16)         // f16 out (conv2, linear channels)
{
    __shared__ alignas(16) uint8_t Ald[2][64 * 128];
    __shared__ alignas(16) uint8_t Bld[2][128 * 128];
    int t = threadIdx.x;
    int l = t & 63;
    int wid = t >> 6;
    // XCD-aware swizzle: 528 = 8 * 66, bijective.
    int bid = (blockIdx.x & 7) * 66 + (blockIdx.x >> 3);
    int bm = bid & 3;
    int bn = bid >> 2;
    int p0 = bn * 128;
    int wm = wid >> 1, wn = wid & 1;
    int swz = (l & 7) ^ (l >> 3);

    const uint8_t* asrc = wp + (size_t)(bm*64 + wid*16 + (l >> 3)) * 2304 + swz * 16;
    size_t bsrc[4];
    #pragma unroll
    for (int i = 0; i < 4; ++i) {
        int p = p0 + wid*32 + i*8 + (l >> 3);
        int n = p / 2816; int rem = p - n * 2816;
        int hh = rem / 88; int ww = rem - hh * 88;
        bsrc[i] = (size_t)((n*34 + hh) * 90 + ww) * 256 + swz * 16;
    }
    int aoff = wid * 2048 + l * 16;
    int boff = wid * 4096 + l * 16;

    floatx4 acc[2][4] = {};

    auto stage = [&](int win, uint8_t* Ab, uint8_t* Bb) {
        int tap = win >> 1;
        int koff = ((tap/3) * 90 + (tap%3)) * 256 + (win & 1) * 128;
        const uint8_t* aw = asrc + win * 128;
        gld16(aw,             Ab + aoff);
        gld16(aw + 8 * 2304,  Ab + aoff + 1024);
        #pragma unroll
        for (int j = 0; j < 4; ++j)
            gld16(xin + bsrc[j] + koff, Bb + boff + j * 1024);
    };
    auto compute = [&](const uint8_t* Ab, const uint8_t* Bb) {
        #pragma unroll
        for (int P = 0; P < 2; ++P) {
            i64x2 af[2], bf[4];
            int sl = (((P << 2) | (l >> 4)) ^ (l & 7)) * 16;
            #pragma unroll
            for (int m = 0; m < 2; ++m) {
                int row = wm*32 + m*16 + (l & 15);
                af[m] = *(const i64x2*)&Ab[row * 128 + sl];
            }
            #pragma unroll
            for (int n = 0; n < 4; ++n) {
                int row = wn*64 + n*16 + (l & 15);
                bf[n] = *(const i64x2*)&Bb[row * 128 + sl];
            }
            __builtin_amdgcn_s_setprio(1);
            #pragma unroll
            for (int m = 0; m < 2; ++m)
                #pragma unroll
                for (int n = 0; n < 4; ++n) {
                    acc[m][n] = __builtin_amdgcn_mfma_f32_16x16x32_fp8_fp8(af[m].x, bf[n].x, acc[m][n], 0, 0, 0);
                    acc[m][n] = __builtin_amdgcn_mfma_f32_16x16x32_fp8_fp8(af[m].y, bf[n].y, acc[m][n], 0, 0, 0);
                }
            __builtin_amdgcn_s_setprio(0);
        }
    };

    stage(0, Ald[0], Bld[0]);
    stage(1, Ald[1], Bld[1]);
    // steady state: 12 loads in flight; BAR6 retires the stage issued one
    // window ago while the newest 6 loads stay in flight across the barrier.
    #pragma unroll 1
    for (int win = 0; win < 16; win += 2) {
        PIPE_BAR6(); compute(Ald[0], Bld[0]);
        PIPE_BARL(); stage(win + 2, Ald[0], Bld[0]);
        PIPE_BAR6(); compute(Ald[1], Bld[1]);
        PIPE_BARL(); stage(win + 3, Ald[1], Bld[1]);
    }
    PIPE_BAR6(); compute(Ald[0], Bld[0]);   // win 16
    PIPE_BAR0(); compute(Ald[1], Bld[1]);   // win 17

    int ocb = bm*64 + wm*32;
    #pragma unroll
    for (int m = 0; m < 2; ++m) {
        int oc0 = ocb + m*16 + (l >> 4) * 4;
        float4 av = *(const float4*)&ab[abOff + oc0];
        float4 bv = *(const float4*)&ab[abOff + 256 + oc0];
        #pragma unroll
        for (int n = 0; n < 4; ++n) {
            int p = p0 + wn*64 + n*16 + (l & 15);
            int ni = p / 2816; int rem = p - ni * 2816;
            int hh = rem / 88; int ww = rem - hh * 88;
            size_t pxb = (size_t)((ni*34 + hh + 1) * 90 + (ww + 1)) * 256;
            float v0 = fmaxf(fmaf(acc[m][n][0], av.x, bv.x), 0.0f);
            float v1 = fmaxf(fmaf(acc[m][n][1], av.y, bv.y), 0.0f);
            float v2 = fmaxf(fmaf(acc[m][n][2], av.z, bv.z), 0.0f);
            float v3 = fmaxf(fmaf(acc[m][n][3], av.w, bv.w), 0.0f);
            if (FP8OUT) {
                uint32_t u = (uint32_t)f2fp8(v0)
                           | ((uint32_t)f2fp8(v1) << 8)
                           | ((uint32_t)f2fp8(v2) << 16)
                           | ((uint32_t)f2fp8(v3) << 24);
                *(uint32_t*)&yout8[pxb + fp8pos(oc0)] = u;
            } else {
                half4v hv;
                hv[0] = (f16)v0; hv[1] = (f16)v1; hv[2] = (f16)v2; hv[3] = (f16)v3;
                *(half4v*)&yout16[pxb + oc0] = hv;
            }
        }
    }
}

// ---------------- fused conv3 + splat (+ geom tail blocks) ----------------
// Blocks 0..2111: 8 px each. Stage y2 rows (4 KB) into LDS; threads 0..129
// each own one w3 output channel and compute 8 dot-256 products (y2 LDS reads
// are wave-broadcast; w3 rows are L2-hot, 66 KB). mu/ls/f land in LDS; then
// the R6 normalize + 1024B-contiguous nontemporal-write phase runs from LDS.
// The ~8 us of GEMM VALU hides under the 55 us write stream.
// Blocks 2112..5015: geom (independent output, fills the write-bound tail).
__global__ __launch_bounds__(256) void splat_fused(
        const f16* __restrict__ y2,   // padded NHWC f16 [6][34][90][256]
        const f16* __restrict__ wp3,  // [192][256] rows: 0=mu,1=ls,2..129=f
        const float* __restrict__ b3p,
        const float* __restrict__ rot, const float* __restrict__ trans,
        const float* __restrict__ K, const float* __restrict__ prot,
        const float* __restrict__ ptrans,
        float* __restrict__ out)
{
    int t = threadIdx.x;
    int bid = blockIdx.x;
    if (bid >= 2112) {                 // geom tail
        int idx = (bid - 2112) * 256 + t;
        geom_point(idx, rot, trans, K, prot, ptrans, out);
        return;
    }

    __shared__ alignas(16) f16 y2l[8 * 256];      // 4 KB
    __shared__ alignas(16) float fl[8][128];      // 4 KB
    __shared__ float muA[8], lsA[8], rs[8];
    __shared__ float eg[8][44];

    int p0 = bid * 8;
    // stage y2 rows: thread t loads 16 B: px = t>>5, chunk c = t&31
    {
        int px = t >> 5, c = t & 31;
        int p = p0 + px;
        int n = p / 2816; int rem = p - n * 2816;
        int h = rem / 88; int w = rem - h * 88;
        const f16* src = y2 + (size_t)((n*34 + h + 1) * 90 + (w + 1)) * 256 + c * 8;
        gld16(src, (uint8_t*)y2l + t * 16);
    }
    PIPE_BAR0();

    // conv3 GEMM: thread t = output channel (t<130): 8 px dot-256
    if (t < 130) {
        float acc[8] = {};
        const f16* wrow = wp3 + (size_t)t * 256;
        #pragma unroll 4
        for (int c = 0; c < 32; ++c) {
            half8 wv = *(const half8*)&wrow[c * 8];
            #pragma unroll
            for (int px = 0; px < 8; ++px) {
                half8 yv = *(const half8*)&y2l[px * 256 + c * 8];   // broadcast
                #pragma unroll
                for (int j = 0; j < 8; ++j)
                    acc[px] = fmaf((float)wv[j], (float)yv[j], acc[px]);
            }
        }
        float bias = b3p[t];
        if (t == 0) {
            #pragma unroll
            for (int px = 0; px < 8; ++px) muA[px] = acc[px] + bias;
        } else if (t == 1) {
            #pragma unroll
            for (int px = 0; px < 8; ++px) lsA[px] = acc[px] + bias;
        } else {
            #pragma unroll
            for (int px = 0; px < 8; ++px) fl[px][t - 2] = acc[px] + bias;
        }
    }
    __syncthreads();

    // gaussian exp pass
    for (int i = t; i < 352; i += 256) {
        int px = i / 44, d = i - px * 44;
        float sig = expf(lsA[px]) + 1e-6f;
        float z = (d + 1.0f) - muA[px];
        eg[px][d] = expf(-0.5f * z * z / (sig * sig));
    }
    __syncthreads();
    if (t < 8) {
        float s = 0.0f;
        for (int d = 0; d < 44; ++d) s += eg[t][d];
        rs[t] = 1.0f / (s + 1e-6f);
    }
    __syncthreads();

    // write phase (R6 structure): wave stores 1024 B contiguous float4 per d
    int l = t & 63;
    int wid = t >> 6;
    int px = wid * 2 + (l >> 5);          // 0..7
    int ch = (l & 31) * 4;                // 0..124
    int p = p0 + px;
    int n = p / 2816; int rem = p - n * 2816;
    int h = rem / 88; int w = rem - h * 88;
    floatx4 f4 = *(const floatx4*)&fl[px][ch];
    float rsv = rs[px];

    size_t pxb = ((size_t)(n * 44) * 32 + h) * 88 + w;
    float* o1 = out + OUT1_OFF;
    #pragma unroll 4
    for (int d = 0; d < 44; ++d) {
        float gg = eg[px][d] * rsv;
        floatx4 v;
        v.x = gg * f4.x; v.y = gg * f4.y; v.z = gg * f4.z; v.w = gg * f4.w;
        __builtin_nontemporal_store(v, (floatx4*)&o1[(pxb + (size_t)d * 2816) * 128 + ch]);
    }
}

// ---------------- launch ----------------
extern "C" void kernel_launch(void* const* d_in, const int* in_sizes, int n_in,
                              void* d_out, int out_size, void* d_ws, size_t ws_size,
                              hipStream_t stream) {
    const float* rot    = (const float*)d_in[0];
    const float* trans  = (const float*)d_in[1];
    const float* K      = (const float*)d_in[2];
    const float* prot   = (const float*)d_in[3];
    const float* ptrans = (const float*)d_in[4];
    const float* feats  = (const float*)d_in[5];
    const float* w1     = (const float*)d_in[6];
    const float* b1     = (const float*)d_in[7];
    const float* g1     = (const float*)d_in[8];
    const float* be1    = (const float*)d_in[9];
    const float* m1     = (const float*)d_in[10];
    const float* v1     = (const float*)d_in[11];
    const float* w2     = (const float*)d_in[12];
    const float* b2     = (const float*)d_in[13];
    const float* g2     = (const float*)d_in[14];
    const float* be2    = (const float*)d_in[15];
    const float* m2     = (const float*)d_in[16];
    const float* v2     = (const float*)d_in[17];
    const float* w3     = (const float*)d_in[18];
    const float* b3     = (const float*)d_in[19];

    char* ws = (char*)d_ws;
    float*   ab    = (float*)(ws + AB_OFF);
    f16*     w3p   = (f16*)(ws + W3P_OFF);
    uint8_t* w1p8  = (uint8_t*)(ws + W1P_OFF);
    uint8_t* w2p8  = (uint8_t*)(ws + W2P_OFF);
    uint8_t* xpad8 = (uint8_t*)(ws + XPAD_OFF);
    uint8_t* y1p8  = (uint8_t*)(ws + Y1P8_OFF);
    f16*     y2    = (f16*)(ws + Y1P_OFF);
    float*   out   = (float*)d_out;

    fused_prep<<<1485, 256, 0, stream>>>(
        feats, w1, w2, w3,
        b1, g1, be1, m1, v1, b2, g2, be2, m2, v2, b3,
        w1p8, w2p8, w3p, ab, xpad8, y1p8);
    conv8_mfma<true><<<528, 256, 0, stream>>>(xpad8, w1p8, ab, 0, y1p8, nullptr);
    conv8_mfma<false><<<528, 256, 0, stream>>>(y1p8, w2p8, ab, 512, nullptr, y2);
    splat_fused<<<5016, 256, 0, stream>>>(y2, w3p, ab + 1024,
                                          rot, trans, K, prot, ptrans, out);
}

// Round 8
// 131.050 us; speedup vs baseline: 1.1494x; 1.1494x over previous
//
#include <hip/hip_runtime.h>
#include <hip/hip_fp16.h>
#include <hip/hip_fp8.h>
#include <stdint.h>

typedef _Float16 f16;
typedef _Float16 half8 __attribute__((ext_vector_type(8)));
typedef _Float16 half4v __attribute__((ext_vector_type(4)));
typedef float floatx4 __attribute__((ext_vector_type(4)));
typedef long long i64;
typedef long long i64x2 __attribute__((ext_vector_type(2)));

#define NCAM 6
#define NPIX 16896          // 6*32*88
#define CIN 256
#define OUT1_OFF 2230272    // geom elements before 'out'

// workspace byte offsets
#define AB_OFF     4096
#define W3P_OFF    16384
#define W1P_OFF    163840
#define W2P_OFF    1343488
#define XPAD_OFF   2523136
#define Y1P_OFF    11923456
#define XPAD8_BYTES 4700160  // 6*34*90*256 fp8
#define Y1P8_OFF   (XPAD_OFF + XPAD8_BYTES)
#define Y3_WS_OFF  21323776
#define Y3_BYTES   8921088   // 16896*132*4

// counted-vmcnt pipeline barriers. Single asm block so no memory op can be
// scheduled between the wait and the barrier.
#define PIPE_BAR6()  asm volatile("s_waitcnt vmcnt(6) lgkmcnt(0)\n\ts_barrier" ::: "memory")
#define PIPE_BAR0()  asm volatile("s_waitcnt vmcnt(0) lgkmcnt(0)\n\ts_barrier" ::: "memory")
// WAR barrier before re-staging a buffer: drain own LDS reads, no vmcnt drain.
#define PIPE_BARL()  asm volatile("s_waitcnt lgkmcnt(0)\n\ts_barrier" ::: "memory")

// ---------------- async global->LDS ----------------
__device__ __forceinline__ void gld16(const void* gsrc, void* ldst) {
    typedef __attribute__((address_space(1))) const uint32_t GBuf;
    typedef __attribute__((address_space(3))) uint32_t LBuf;
    __builtin_amdgcn_global_load_lds((GBuf*)(uintptr_t)gsrc,
                                     (LBuf*)(uint32_t)(uintptr_t)ldst,
                                     16, 0, 0);
}

__device__ __forceinline__ uint8_t f2fp8(float v) {
    __hip_fp8_e4m3 q(v);
    return (uint8_t)q.__x;
}

// fp8 channel permutation within a 128-block (so one 16B LDS slot holds the
// two 8B K-fragments kk=2P and kk=2P+1 of one kslot):
// c128 = (2P+kh)*32 + ks*8 + jj  ->  pos128 = (P*4+ks)*16 + kh*8 + jj
__device__ __forceinline__ int fp8pos(int c) {
    int c128 = c & 127;
    int P  = c128 >> 6;
    int kh = (c128 >> 5) & 1;
    int ks = (c128 >> 3) & 3;
    return (c >> 7) * 128 + (P * 4 + ks) * 16 + kh * 8 + (c & 7);
}

// ---------------- 3x3 inverse ----------------
__device__ __forceinline__ void inv3(const float* m, float* o) {
    float a=m[0],b=m[1],c=m[2],d=m[3],e=m[4],f=m[5],g=m[6],h=m[7],i=m[8];
    float A  =  (e*i - f*h);
    float Bc = -(d*i - f*g);
    float Cc =  (d*h - e*g);
    float det = a*A + b*Bc + c*Cc;
    float r = 1.0f/det;
    o[0]=A*r;   o[1]=-(b*i - c*h)*r; o[2]= (b*f - c*e)*r;
    o[3]=Bc*r;  o[4]= (a*i - c*g)*r; o[5]=-(a*f - c*d)*r;
    o[6]=Cc*r;  o[7]=-(a*h - b*g)*r; o[8]= (a*e - b*d)*r;
}

// geom for one flat index, matrices recomputed (cheap, broadcast loads)
__device__ __forceinline__ void geom_point(int idx,
        const float* __restrict__ rot, const float* __restrict__ trans,
        const float* __restrict__ K, const float* __restrict__ prot,
        const float* __restrict__ ptrans, float* __restrict__ out) {
    int w = idx % 88;
    int h = (idx / 88) % 32;
    int d = (idx / 2816) % 44;
    int n = idx / 123904;
    float P[9], Km[9], R[9], iP[9], iK[9], C[9];
    #pragma unroll
    for (int i = 0; i < 9; ++i) { P[i]=prot[n*9+i]; Km[i]=K[n*9+i]; R[i]=rot[n*9+i]; }
    inv3(P, iP);
    inv3(Km, iK);
    #pragma unroll
    for (int i = 0; i < 3; ++i)
        #pragma unroll
        for (int j = 0; j < 3; ++j)
            C[i*3+j] = R[i*3+0]*iK[0*3+j] + R[i*3+1]*iK[1*3+j] + R[i*3+2]*iK[2*3+j];
    float fx = w * (703.0f / 87.0f);
    float fy = h * (255.0f / 31.0f);
    float fz = d + 1.0f;
    float px = fx - ptrans[n*3+0], py = fy - ptrans[n*3+1], pz = fz - ptrans[n*3+2];
    float q0 = iP[0]*px + iP[1]*py + iP[2]*pz;
    float q1 = iP[3]*px + iP[4]*py + iP[5]*pz;
    float q2 = iP[6]*px + iP[7]*py + iP[8]*pz;
    float r0 = q0 * q2, r1 = q1 * q2, r2 = q2;
    out[idx*3 + 0] = C[0]*r0 + C[1]*r1 + C[2]*r2 + trans[n*3+0];
    out[idx*3 + 1] = C[3]*r0 + C[4]*r1 + C[5]*r2 + trans[n*3+1];
    out[idx*3 + 2] = C[6]*r0 + C[7]*r1 + C[8]*r2 + trans[n*3+2];
}

// ---------------- fused prep: border-zero + wperm + xpad + ab ----------------
// blocks 0..11      : zero fp8 pad borders of xpad8 (0..5) and y1p8 (6..11)
// blocks 12..715    : weight permute->fp8 (oc = bid-12; 512 for w1/w2) / w3p f16 (last 192)
// blocks 716..1483  : NCHW->NHWC-fp8 transpose of feats (one (n,h,icg) per block)
// block  1484       : folded BN coeffs (w-scale 1/16 folded) + padded b3
// (geom lives in the splat tail - off the prep->conv1 critical path)
__global__ __launch_bounds__(256) void fused_prep(
        const float* __restrict__ feats,
        const float* __restrict__ w1, const float* __restrict__ w2,
        const float* __restrict__ w3,
        const float* __restrict__ b1, const float* __restrict__ g1,
        const float* __restrict__ be1, const float* __restrict__ m1, const float* __restrict__ v1,
        const float* __restrict__ b2, const float* __restrict__ g2,
        const float* __restrict__ be2, const float* __restrict__ m2, const float* __restrict__ v2,
        const float* __restrict__ b3,
        uint8_t* __restrict__ w1p, uint8_t* __restrict__ w2p, f16* __restrict__ w3p,
        float* __restrict__ ab, uint8_t* __restrict__ xpad8, uint8_t* __restrict__ y1p8) {
    int bid = blockIdx.x;
    int t = threadIdx.x;
    if (bid < 12) {
        // zero only the pad border (interior written by transpose / conv epilogues)
        uint8_t* buf = (bid < 6) ? xpad8 : y1p8;
        int n = bid % 6;
        for (int i = t; i < 3904; i += 256) {      // 244 border pixels * 16 uint4
            int u = i >> 4, c = i & 15;
            int h, w;
            if (u < 90)       { h = 0;       w = u; }
            else if (u < 180) { h = 33;      w = u - 90; }
            else if (u < 212) { h = u - 179; w = 0; }
            else              { h = u - 211; w = 89; }
            *(uint4*)&buf[((size_t)((n*34 + h)*90 + w))*256 + c*16] = uint4{0,0,0,0};
        }
        return;
    }
    if (bid < 716) {
        int oc = bid - 12;                     // 0..703
        if (oc < 512) {
            // fp8 weight, x16 scaled, laid out [oc][win(18)][slot(8)][16B]
            const float* s = ((oc < 256) ? w1 : w2) + (size_t)(oc & 255) * 2304;
            uint8_t* dst = ((oc < 256) ? w1p : w2p) + (size_t)(oc & 255) * 2304;
            for (int idx = t; idx < 2304; idx += 256) {
                int win = idx >> 7, b = idx & 127;
                int sl = b >> 4, j = b & 15;
                int P = sl >> 2, ks = sl & 3, kh = j >> 3, jj = j & 7;
                int kwin = (2*P + kh)*32 + ks*8 + jj;
                int Kg = win*128 + kwin;
                int tap = Kg >> 8, c = Kg & 255;
                dst[idx] = f2fp8(s[c*9 + tap] * 16.0f);
            }
        } else {
            int r = oc - 512;                  // 0..191
            w3p[r * 256 + t] = (r < 130) ? (f16)w3[r * 256 + t] : (f16)0.0f;
        }
        return;
    }
    if (bid < 1484) {
        __shared__ float tile[64][89];
        int b = bid - 716;                     // 0..767 : (n, h, icg)
        int n = b >> 7;
        int h = (b >> 2) & 31;
        int icg = b & 3;
        int ic0 = icg * 64;
        #pragma unroll
        for (int j = 0; j < 22; ++j) {
            int idx = j * 256 + t;
            int r = idx / 88, w = idx - r * 88;
            tile[r][w] = feats[((size_t)(n*256 + ic0 + r) * 32 + h) * 88 + w];
        }
        __syncthreads();
        // write 88 px * 16 channel-quads as fp8 with fp8pos permutation
        for (int j = 0; j < 6; ++j) {
            int idx = j * 256 + t;
            if (idx < 1408) {
                int w = idx >> 4, cq = idx & 15;
                int c = cq * 4;
                int ca = ic0 + c;
                uint32_t u = (uint32_t)f2fp8(tile[c][w])
                           | ((uint32_t)f2fp8(tile[c+1][w]) << 8)
                           | ((uint32_t)f2fp8(tile[c+2][w]) << 16)
                           | ((uint32_t)f2fp8(tile[c+3][w]) << 24);
                size_t px = (size_t)((n*34 + h + 1) * 90 + (w + 1));
                *(uint32_t*)&xpad8[px*256 + fp8pos(ca)] = u;
            }
        }
        return;
    }
    // bid == 1484
    {
        float a1 = g1[t] * rsqrtf(v1[t] + 1e-3f);
        ab[t]       = a1 * 0.0625f;            // fold 1/16 weight scale
        ab[256 + t] = (b1[t] - m1[t]) * a1 + be1[t];
        float a2 = g2[t] * rsqrtf(v2[t] + 1e-3f);
        ab[512 + t] = a2 * 0.0625f;
        ab[768 + t] = (b2[t] - m2[t]) * a2 + be2[t];
        if (t < 192) ab[1024 + t] = (t < 130) ? b3[t] : 0.0f;
    }
}

// standalone geom (fallback path when y3 must live in d_out)
__global__ void geom_k(const float* __restrict__ rot, const float* __restrict__ trans,
                       const float* __restrict__ K, const float* __restrict__ prot,
                       const float* __restrict__ ptrans, float* __restrict__ out) {
    int idx = blockIdx.x * 256 + threadIdx.x;
    geom_point(idx, rot, trans, K, prot, ptrans, out);
}

// ---------------- conv 3x3 implicit GEMM, fp8 MFMA ----------------
// 256 threads / 4 waves, wave tile 32oc x 64px, double-buffered LDS,
// BAR6/BARL split barriers, setprio, XCD swizzle. fp8 e4m3: K-window = 128
// (18 windows), LDS rows 128B / 8 slots of 16B, XOR swizzle (conflict-free).
// Per window: 12 ds_read_b128 feed 32 MFMAs, 6 gld16 staged.
template<bool FP8OUT>
__global__ __launch_bounds__(256, 3) void conv8_mfma(
        const uint8_t* __restrict__ xin,  // fp8 padded NHWC-perm [6][34][90][256]
        const uint8_t* __restrict__ wp,   // fp8 [256][18][8][16]
        const float* __restrict__ ab, int abOff,
        uint8_t* __restrict__ yout8,      // fp8 out (conv1)
        f16* __restrict__ yout16)         // f16 out (conv2, linear channels)
{
    __shared__ alignas(16) uint8_t Ald[2][64 * 128];
    __shared__ alignas(16) uint8_t Bld[2][128 * 128];
    int t = threadIdx.x;
    int l = t & 63;
    int wid = t >> 6;
    // XCD-aware swizzle: 528 = 8 * 66, bijective.
    int bid = (blockIdx.x & 7) * 66 + (blockIdx.x >> 3);
    int bm = bid & 3;
    int bn = bid >> 2;
    int p0 = bn * 128;
    int wm = wid >> 1, wn = wid & 1;
    int swz = (l & 7) ^ (l >> 3);

    const uint8_t* asrc = wp + (size_t)(bm*64 + wid*16 + (l >> 3)) * 2304 + swz * 16;
    size_t bsrc[4];
    #pragma unroll
    for (int i = 0; i < 4; ++i) {
        int p = p0 + wid*32 + i*8 + (l >> 3);
        int n = p / 2816; int rem = p - n * 2816;
        int hh = rem / 88; int ww = rem - hh * 88;
        bsrc[i] = (size_t)((n*34 + hh) * 90 + ww) * 256 + swz * 16;
    }
    int aoff = wid * 2048 + l * 16;
    int boff = wid * 4096 + l * 16;

    floatx4 acc[2][4] = {};

    auto stage = [&](int win, uint8_t* Ab, uint8_t* Bb) {
        int tap = win >> 1;
        int koff = ((tap/3) * 90 + (tap%3)) * 256 + (win & 1) * 128;
        const uint8_t* aw = asrc + win * 128;
        gld16(aw,             Ab + aoff);
        gld16(aw + 8 * 2304,  Ab + aoff + 1024);
        #pragma unroll
        for (int j = 0; j < 4; ++j)
            gld16(xin + bsrc[j] + koff, Bb + boff + j * 1024);
    };
    auto compute = [&](const uint8_t* Ab, const uint8_t* Bb) {
        #pragma unroll
        for (int P = 0; P < 2; ++P) {
            i64x2 af[2], bf[4];
            int sl = (((P << 2) | (l >> 4)) ^ (l & 7)) * 16;
            #pragma unroll
            for (int m = 0; m < 2; ++m) {
                int row = wm*32 + m*16 + (l & 15);
                af[m] = *(const i64x2*)&Ab[row * 128 + sl];
            }
            #pragma unroll
            for (int n = 0; n < 4; ++n) {
                int row = wn*64 + n*16 + (l & 15);
                bf[n] = *(const i64x2*)&Bb[row * 128 + sl];
            }
            __builtin_amdgcn_s_setprio(1);
            #pragma unroll
            for (int m = 0; m < 2; ++m)
                #pragma unroll
                for (int n = 0; n < 4; ++n) {
                    acc[m][n] = __builtin_amdgcn_mfma_f32_16x16x32_fp8_fp8(af[m].x, bf[n].x, acc[m][n], 0, 0, 0);
                    acc[m][n] = __builtin_amdgcn_mfma_f32_16x16x32_fp8_fp8(af[m].y, bf[n].y, acc[m][n], 0, 0, 0);
                }
            __builtin_amdgcn_s_setprio(0);
        }
    };

    stage(0, Ald[0], Bld[0]);
    stage(1, Ald[1], Bld[1]);
    // steady state: 12 loads in flight; BAR6 retires the stage issued one
    // window ago while the newest 6 loads stay in flight across the barrier.
    #pragma unroll 1
    for (int win = 0; win < 16; win += 2) {
        PIPE_BAR6(); compute(Ald[0], Bld[0]);
        PIPE_BARL(); stage(win + 2, Ald[0], Bld[0]);
        PIPE_BAR6(); compute(Ald[1], Bld[1]);
        PIPE_BARL(); stage(win + 3, Ald[1], Bld[1]);
    }
    PIPE_BAR6(); compute(Ald[0], Bld[0]);   // win 16
    PIPE_BAR0(); compute(Ald[1], Bld[1]);   // win 17

    int ocb = bm*64 + wm*32;
    #pragma unroll
    for (int m = 0; m < 2; ++m) {
        int oc0 = ocb + m*16 + (l >> 4) * 4;
        float4 av = *(const float4*)&ab[abOff + oc0];
        float4 bv = *(const float4*)&ab[abOff + 256 + oc0];
        #pragma unroll
        for (int n = 0; n < 4; ++n) {
            int p = p0 + wn*64 + n*16 + (l & 15);
            int ni = p / 2816; int rem = p - ni * 2816;
            int hh = rem / 88; int ww = rem - hh * 88;
            size_t pxb = (size_t)((ni*34 + hh + 1) * 90 + (ww + 1)) * 256;
            float v0 = fmaxf(fmaf(acc[m][n][0], av.x, bv.x), 0.0f);
            float v1 = fmaxf(fmaf(acc[m][n][1], av.y, bv.y), 0.0f);
            float v2 = fmaxf(fmaf(acc[m][n][2], av.z, bv.z), 0.0f);
            float v3 = fmaxf(fmaf(acc[m][n][3], av.w, bv.w), 0.0f);
            if (FP8OUT) {
                uint32_t u = (uint32_t)f2fp8(v0)
                           | ((uint32_t)f2fp8(v1) << 8)
                           | ((uint32_t)f2fp8(v2) << 16)
                           | ((uint32_t)f2fp8(v3) << 24);
                *(uint32_t*)&yout8[pxb + fp8pos(oc0)] = u;
            } else {
                half4v hv;
                hv[0] = (f16)v0; hv[1] = (f16)v1; hv[2] = (f16)v2; hv[3] = (f16)v3;
                *(half4v*)&yout16[pxb + oc0] = hv;
            }
        }
    }
}

// ---------------- conv3 (1x1) MFMA GEMM f16, counted-vmcnt pipeline ----------------
__global__ __launch_bounds__(256) void conv3_mfma(
        const f16* __restrict__ xin,  // y2 padded NHWC f16 (linear channels)
        const f16* __restrict__ wp3,  // [192][256]
        const float* __restrict__ b3p,
        float* __restrict__ y3)       // [16896][132]
{
    __shared__ alignas(16) f16 Ald[3][64 * 64];
    __shared__ alignas(16) f16 Bld[3][128 * 64];
    int t = threadIdx.x;
    int l = t & 63;
    int wid = t >> 6;
    int bm = blockIdx.x % 3;
    int bn = blockIdx.x / 3;
    int p0 = bn * 128;
    int wm = wid >> 1, wn = wid & 1;
    int swz = (l & 7) ^ (l >> 3);

    const f16* asrc = wp3 + (size_t)(bm*64 + wid*16 + (l >> 3)) * 256 + swz * 8;
    size_t bsrc[4];
    #pragma unroll
    for (int i = 0; i < 4; ++i) {
        int p = p0 + wid*32 + i*8 + (l >> 3);
        int n = p / 2816; int rem = p - n * 2816;
        int hh = rem / 88; int ww = rem - hh * 88;
        bsrc[i] = (size_t)((n*34 + hh) * 90 + ww) * 256 + swz * 8;
    }
    int aoff = wid * 16 * 64;
    int boff = wid * 32 * 64;

    floatx4 acc[2][4] = {};

    auto stage = [&](int kt, f16* Ab, f16* Bb) {
        int koff = (1 * 90 + 1) * 256 + kt * 64;
        int k0 = kt * 64;
        gld16(asrc + k0,            Ab + aoff);
        gld16(asrc + k0 + 8 * 256,  Ab + aoff + 8 * 64);
        gld16(xin + bsrc[0] + koff, Bb + boff);
        gld16(xin + bsrc[1] + koff, Bb + boff + 8 * 64);
        gld16(xin + bsrc[2] + koff, Bb + boff + 16 * 64);
        gld16(xin + bsrc[3] + koff, Bb + boff + 24 * 64);
    };
    auto compute = [&](const f16* Ab, const f16* Bb) {
        #pragma unroll
        for (int kk = 0; kk < 2; ++kk) {
            half8 af[2], bf[4];
            int kslot = kk * 4 + (l >> 4);
            #pragma unroll
            for (int m = 0; m < 2; ++m) {
                int row = wm*32 + m*16 + (l & 15);
                af[m] = *(const half8*)&Ab[row * 64 + ((kslot ^ (row & 7)) * 8)];
            }
            #pragma unroll
            for (int n = 0; n < 4; ++n) {
                int row = wn*64 + n*16 + (l & 15);
                bf[n] = *(const half8*)&Bb[row * 64 + ((kslot ^ (row & 7)) * 8)];
            }
            __builtin_amdgcn_s_setprio(1);
            #pragma unroll
            for (int m = 0; m < 2; ++m)
                #pragma unroll
                for (int n = 0; n < 4; ++n)
                    acc[m][n] = __builtin_amdgcn_mfma_f32_16x16x32_f16(af[m], bf[n], acc[m][n], 0, 0, 0);
            __builtin_amdgcn_s_setprio(0);
        }
    };

    stage(0, Ald[0], Bld[0]);
    stage(1, Ald[1], Bld[1]);
    PIPE_BAR6(); stage(2, Ald[2], Bld[2]); compute(Ald[0], Bld[0]);  // kt=0
    PIPE_BAR6(); stage(3, Ald[0], Bld[0]); compute(Ald[1], Bld[1]);  // kt=1
    PIPE_BAR6(); compute(Ald[2], Bld[2]);                            // kt=2
    PIPE_BAR0(); compute(Ald[0], Bld[0]);                            // kt=3

    int ocb = bm*64 + wm*32;
    #pragma unroll
    for (int m = 0; m < 2; ++m) {
        int oc0 = ocb + m*16 + (l >> 4) * 4;
        if (oc0 < 132) {
            float4 bv = *(const float4*)&b3p[oc0];
            #pragma unroll
            for (int n = 0; n < 4; ++n) {
                int p = p0 + wn*64 + n*16 + (l & 15);
                float4 v;
                v.x = acc[m][n][0] + bv.x;
                v.y = acc[m][n][1] + bv.y;
                v.z = acc[m][n][2] + bv.z;
                v.w = acc[m][n][3] + bv.w;
                *(float4*)&y3[(size_t)p * 132 + oc0] = v;
            }
        }
    }
}

// ---------------- splat: gaussian expand + write (+ geom tail) ----------------
// Blocks 0..2111: 8 px/block (2 px per wave, 4 ch per lane): each wave stores
// 1024 B contiguous float4 per d-step, nontemporal. Gaussian normalization
// via LDS pre-pass. Blocks 2112+: geom (independent output; its VALU + 8.9 MB
// of writes hide inside the write-bound splat window).
__global__ __launch_bounds__(256) void splat_k(
        const float* __restrict__ y3, // [16896][132]: mu, ls, f0..f127
        const float* __restrict__ rot, const float* __restrict__ trans,
        const float* __restrict__ K, const float* __restrict__ prot,
        const float* __restrict__ ptrans,
        float* __restrict__ out)
{
    int t = threadIdx.x;
    int bid = blockIdx.x;
    if (bid >= 2112) {                 // geom tail
        int idx = (bid - 2112) * 256 + t;
        geom_point(idx, rot, trans, K, prot, ptrans, out);
        return;
    }

    __shared__ float eg[8][44];
    __shared__ float rs[8];
    int p0 = bid * 8;

    // pass 1: exp values for 8 px x 44 depths
    for (int i = t; i < 352; i += 256) {
        int px = i / 44, d = i - px * 44;
        const float* row = y3 + (size_t)(p0 + px) * 132;
        float mu = row[0];
        float sig = expf(row[1]) + 1e-6f;
        float z = (d + 1.0f) - mu;
        eg[px][d] = expf(-0.5f * z * z / (sig * sig));
    }
    __syncthreads();
    if (t < 8) {
        float s = 0.0f;
        for (int d = 0; d < 44; ++d) s += eg[t][d];
        rs[t] = 1.0f / (s + 1e-6f);
    }
    __syncthreads();

    int l = t & 63;
    int wid = t >> 6;
    int px = wid * 2 + (l >> 5);          // 0..7
    int ch = (l & 31) * 4;                // 0..124
    int p = p0 + px;
    int n = p / 2816; int rem = p - n * 2816;
    int h = rem / 88; int w = rem - h * 88;
    const float* row = y3 + (size_t)p * 132;
    floatx4 f4 = *(const floatx4*)&row[2 + ch];   // 8B-aligned dwordx4 (legal)
    float rsv = rs[px];

    size_t pxb = ((size_t)(n * 44) * 32 + h) * 88 + w;
    float* o1 = out + OUT1_OFF;
    #pragma unroll 4
    for (int d = 0; d < 44; ++d) {
        float gg = eg[px][d] * rsv;
        floatx4 v;
        v.x = gg * f4.x; v.y = gg * f4.y; v.z = gg * f4.z; v.w = gg * f4.w;
        __builtin_nontemporal_store(v, (floatx4*)&o1[(pxb + (size_t)d * 2816) * 128 + ch]);
    }
}

// ---------------- launch ----------------
extern "C" void kernel_launch(void* const* d_in, const int* in_sizes, int n_in,
                              void* d_out, int out_size, void* d_ws, size_t ws_size,
                              hipStream_t stream) {
    const float* rot    = (const float*)d_in[0];
    const float* trans  = (const float*)d_in[1];
    const float* K      = (const float*)d_in[2];
    const float* prot   = (const float*)d_in[3];
    const float* ptrans = (const float*)d_in[4];
    const float* feats  = (const float*)d_in[5];
    const float* w1     = (const float*)d_in[6];
    const float* b1     = (const float*)d_in[7];
    const float* g1     = (const float*)d_in[8];
    const float* be1    = (const float*)d_in[9];
    const float* m1     = (const float*)d_in[10];
    const float* v1     = (const float*)d_in[11];
    const float* w2     = (const float*)d_in[12];
    const float* b2     = (const float*)d_in[13];
    const float* g2     = (const float*)d_in[14];
    const float* be2    = (const float*)d_in[15];
    const float* m2     = (const float*)d_in[16];
    const float* v2     = (const float*)d_in[17];
    const float* w3     = (const float*)d_in[18];
    const float* b3     = (const float*)d_in[19];

    char* ws = (char*)d_ws;
    float*   ab    = (float*)(ws + AB_OFF);
    f16*     w3p   = (f16*)(ws + W3P_OFF);
    uint8_t* w1p8  = (uint8_t*)(ws + W1P_OFF);
    uint8_t* w2p8  = (uint8_t*)(ws + W2P_OFF);
    uint8_t* xpad8 = (uint8_t*)(ws + XPAD_OFF);
    uint8_t* y1p8  = (uint8_t*)(ws + Y1P8_OFF);
    f16*     y2    = (f16*)(ws + Y1P_OFF);
    float*   out   = (float*)d_out;

    bool y3InWs = ws_size >= (size_t)(Y3_WS_OFF + Y3_BYTES);
    float* y3 = y3InWs ? (float*)(ws + Y3_WS_OFF) : out;

    fused_prep<<<1485, 256, 0, stream>>>(
        feats, w1, w2, w3,
        b1, g1, be1, m1, v1, b2, g2, be2, m2, v2, b3,
        w1p8, w2p8, w3p, ab, xpad8, y1p8);
    conv8_mfma<true><<<528, 256, 0, stream>>>(xpad8, w1p8, ab, 0, y1p8, nullptr);
    conv8_mfma<false><<<528, 256, 0, stream>>>(y1p8, w2p8, ab, 512, nullptr, y2);
    conv3_mfma<<<396, 256, 0, stream>>>(y2, w3p, ab + 1024, y3);
    if (y3InWs) {
        // geom rides in the splat tail (write-bound window hides it)
        splat_k<<<2112 + 2904, 256, 0, stream>>>(y3, rot, trans, K, prot, ptrans, out);
    } else {
        splat_k<<<2112, 256, 0, stream>>>(y3, rot, trans, K, prot, ptrans, out);
        geom_k<<<2904, 256, 0, stream>>>(rot, trans, K, prot, ptrans, out);
    }
}

// Round 9
// 130.336 us; speedup vs baseline: 1.1557x; 1.0055x over previous
//
#include <hip/hip_runtime.h>
#include <hip/hip_fp16.h>
#include <hip/hip_fp8.h>
#include <stdint.h>

typedef _Float16 f16;
typedef _Float16 half8 __attribute__((ext_vector_type(8)));
typedef _Float16 half4v __attribute__((ext_vector_type(4)));
typedef float floatx4 __attribute__((ext_vector_type(4)));
typedef long long i64;
typedef long long i64x2 __attribute__((ext_vector_type(2)));

#define NCAM 6
#define NPIX 16896          // 6*32*88
#define CIN 256
#define OUT1_OFF 2230272    // geom elements before 'out'

// workspace byte offsets
#define AB_OFF     4096
#define W3P_OFF    16384
#define W1P_OFF    163840
#define W2P_OFF    1343488
#define XPAD_OFF   2523136
#define Y1P_OFF    11923456
#define XPAD8_BYTES 4700160  // 6*34*90*256 fp8
#define Y1P8_OFF   (XPAD_OFF + XPAD8_BYTES)
#define Y3_WS_OFF  21323776
#define Y3_BYTES   8921088   // 16896*132*4

// counted-vmcnt pipeline barriers. Single asm block so no memory op can be
// scheduled between the wait and the barrier.
#define PIPE_BAR6()  asm volatile("s_waitcnt vmcnt(6) lgkmcnt(0)\n\ts_barrier" ::: "memory")
#define PIPE_BAR0()  asm volatile("s_waitcnt vmcnt(0) lgkmcnt(0)\n\ts_barrier" ::: "memory")
// WAR barrier before re-staging a buffer: drain own LDS reads, no vmcnt drain.
#define PIPE_BARL()  asm volatile("s_waitcnt lgkmcnt(0)\n\ts_barrier" ::: "memory")

// ---------------- async global->LDS ----------------
__device__ __forceinline__ void gld16(const void* gsrc, void* ldst) {
    typedef __attribute__((address_space(1))) const uint32_t GBuf;
    typedef __attribute__((address_space(3))) uint32_t LBuf;
    __builtin_amdgcn_global_load_lds((GBuf*)(uintptr_t)gsrc,
                                     (LBuf*)(uint32_t)(uintptr_t)ldst,
                                     16, 0, 0);
}

// hardware packed f32->fp8(e4m3, OCP on gfx950) conversion: 4 values -> u32
__device__ __forceinline__ uint32_t pk4_fp8(float a, float b, float c, float d) {
    int u = __builtin_amdgcn_cvt_pk_fp8_f32(a, b, 0, false);   // bytes 0,1
    u = __builtin_amdgcn_cvt_pk_fp8_f32(c, d, u, true);        // bytes 2,3
    return (uint32_t)u;
}

// fp8 channel permutation within a 128-block (so one 16B LDS slot holds the
// two 8B K-fragments kk=2P and kk=2P+1 of one kslot):
// c128 = (2P+kh)*32 + ks*8 + jj  ->  pos128 = (P*4+ks)*16 + kh*8 + jj
__device__ __forceinline__ int fp8pos(int c) {
    int c128 = c & 127;
    int P  = c128 >> 6;
    int kh = (c128 >> 5) & 1;
    int ks = (c128 >> 3) & 3;
    return (c >> 7) * 128 + (P * 4 + ks) * 16 + kh * 8 + (c & 7);
}

// ---------------- 3x3 inverse ----------------
__device__ __forceinline__ void inv3(const float* m, float* o) {
    float a=m[0],b=m[1],c=m[2],d=m[3],e=m[4],f=m[5],g=m[6],h=m[7],i=m[8];
    float A  =  (e*i - f*h);
    float Bc = -(d*i - f*g);
    float Cc =  (d*h - e*g);
    float det = a*A + b*Bc + c*Cc;
    float r = 1.0f/det;
    o[0]=A*r;   o[1]=-(b*i - c*h)*r; o[2]= (b*f - c*e)*r;
    o[3]=Bc*r;  o[4]= (a*i - c*g)*r; o[5]=-(a*f - c*d)*r;
    o[6]=Cc*r;  o[7]=-(a*h - b*g)*r; o[8]= (a*e - b*d)*r;
}

// geom for one flat index, matrices recomputed (cheap, broadcast loads)
__device__ __forceinline__ void geom_point(int idx,
        const float* __restrict__ rot, const float* __restrict__ trans,
        const float* __restrict__ K, const float* __restrict__ prot,
        const float* __restrict__ ptrans, float* __restrict__ out) {
    int w = idx % 88;
    int h = (idx / 88) % 32;
    int d = (idx / 2816) % 44;
    int n = idx / 123904;
    float P[9], Km[9], R[9], iP[9], iK[9], C[9];
    #pragma unroll
    for (int i = 0; i < 9; ++i) { P[i]=prot[n*9+i]; Km[i]=K[n*9+i]; R[i]=rot[n*9+i]; }
    inv3(P, iP);
    inv3(Km, iK);
    #pragma unroll
    for (int i = 0; i < 3; ++i)
        #pragma unroll
        for (int j = 0; j < 3; ++j)
            C[i*3+j] = R[i*3+0]*iK[0*3+j] + R[i*3+1]*iK[1*3+j] + R[i*3+2]*iK[2*3+j];
    float fx = w * (703.0f / 87.0f);
    float fy = h * (255.0f / 31.0f);
    float fz = d + 1.0f;
    float px = fx - ptrans[n*3+0], py = fy - ptrans[n*3+1], pz = fz - ptrans[n*3+2];
    float q0 = iP[0]*px + iP[1]*py + iP[2]*pz;
    float q1 = iP[3]*px + iP[4]*py + iP[5]*pz;
    float q2 = iP[6]*px + iP[7]*py + iP[8]*pz;
    float r0 = q0 * q2, r1 = q1 * q2, r2 = q2;
    out[idx*3 + 0] = C[0]*r0 + C[1]*r1 + C[2]*r2 + trans[n*3+0];
    out[idx*3 + 1] = C[3]*r0 + C[4]*r1 + C[5]*r2 + trans[n*3+1];
    out[idx*3 + 2] = C[6]*r0 + C[7]*r1 + C[8]*r2 + trans[n*3+2];
}

// ---------------- fused prep: border-zero + wperm + xpad + ab ----------------
// blocks 0..11      : zero fp8 pad borders of xpad8 (0..5) and y1p8 (6..11)
// blocks 12..715    : weight permute->fp8 (oc = bid-12; 512 for w1/w2,
//                     LDS-staged coalesced read + hw pk4 convert) / w3p f16 (last 192)
// blocks 716..1483  : NCHW->NHWC-fp8 transpose of feats (one (n,h,icg) per block)
// block  1484       : folded BN coeffs (w-scale 1/16 folded) + padded b3
// (geom lives in the splat tail - off the prep->conv1 critical path)
__global__ __launch_bounds__(256) void fused_prep(
        const float* __restrict__ feats,
        const float* __restrict__ w1, const float* __restrict__ w2,
        const float* __restrict__ w3,
        const float* __restrict__ b1, const float* __restrict__ g1,
        const float* __restrict__ be1, const float* __restrict__ m1, const float* __restrict__ v1,
        const float* __restrict__ b2, const float* __restrict__ g2,
        const float* __restrict__ be2, const float* __restrict__ m2, const float* __restrict__ v2,
        const float* __restrict__ b3,
        uint8_t* __restrict__ w1p, uint8_t* __restrict__ w2p, f16* __restrict__ w3p,
        float* __restrict__ ab, uint8_t* __restrict__ xpad8, uint8_t* __restrict__ y1p8) {
    __shared__ float shf[64 * 89];     // transpose tile / wperm staging (22.8 KB)
    int bid = blockIdx.x;
    int t = threadIdx.x;
    if (bid < 12) {
        // zero only the pad border (interior written by transpose / conv epilogues)
        uint8_t* buf = (bid < 6) ? xpad8 : y1p8;
        int n = bid % 6;
        for (int i = t; i < 3904; i += 256) {      // 244 border pixels * 16 uint4
            int u = i >> 4, c = i & 15;
            int h, w;
            if (u < 90)       { h = 0;       w = u; }
            else if (u < 180) { h = 33;      w = u - 90; }
            else if (u < 212) { h = u - 179; w = 0; }
            else              { h = u - 211; w = 89; }
            *(uint4*)&buf[((size_t)((n*34 + h)*90 + w))*256 + c*16] = uint4{0,0,0,0};
        }
        return;
    }
    if (bid < 716) {
        int oc = bid - 12;                     // 0..703
        if (oc < 512) {
            // fp8 weight, x16 scaled, laid out [oc][win(18)][slot(8)][16B].
            // Stage the 9KB source row coalesced into LDS, then gather+pk4.
            const float* s = ((oc < 256) ? w1 : w2) + (size_t)(oc & 255) * 2304;
            uint8_t* dst = ((oc < 256) ? w1p : w2p) + (size_t)(oc & 255) * 2304;
            for (int k = t; k < 2304; k += 256) shf[k] = s[k];
            __syncthreads();
            uint32_t* dst32 = (uint32_t*)dst;
            for (int i4 = t; i4 < 576; i4 += 256) {
                int idx = i4 * 4;
                int win = idx >> 7, b = idx & 127;
                int sl = b >> 4, j0 = b & 15;          // j0 in {0,4,8,12}
                float v[4];
                #pragma unroll
                for (int jo = 0; jo < 4; ++jo) {
                    int j = j0 + jo;
                    int P = sl >> 2, ks = sl & 3, kh = j >> 3, jj = j & 7;
                    int kwin = (2*P + kh)*32 + ks*8 + jj;
                    int Kg = win*128 + kwin;
                    int tap = Kg >> 8, c = Kg & 255;
                    v[jo] = shf[c*9 + tap] * 16.0f;
                }
                dst32[i4] = pk4_fp8(v[0], v[1], v[2], v[3]);
            }
        } else {
            int r = oc - 512;                  // 0..191
            w3p[r * 256 + t] = (r < 130) ? (f16)w3[r * 256 + t] : (f16)0.0f;
        }
        return;
    }
    if (bid < 1484) {
        int b = bid - 716;                     // 0..767 : (n, h, icg)
        int n = b >> 7;
        int h = (b >> 2) & 31;
        int icg = b & 3;
        int ic0 = icg * 64;
        #pragma unroll
        for (int j = 0; j < 22; ++j) {
            int idx = j * 256 + t;
            int r = idx / 88, w = idx - r * 88;
            shf[r * 89 + w] = feats[((size_t)(n*256 + ic0 + r) * 32 + h) * 88 + w];
        }
        __syncthreads();
        // write 88 px * 16 channel-quads as fp8 with fp8pos permutation (hw pk4)
        for (int j = 0; j < 6; ++j) {
            int idx = j * 256 + t;
            if (idx < 1408) {
                int w = idx >> 4, cq = idx & 15;
                int c = cq * 4;
                int ca = ic0 + c;
                uint32_t u = pk4_fp8(shf[c*89 + w], shf[(c+1)*89 + w],
                                     shf[(c+2)*89 + w], shf[(c+3)*89 + w]);
                size_t px = (size_t)((n*34 + h + 1) * 90 + (w + 1));
                *(uint32_t*)&xpad8[px*256 + fp8pos(ca)] = u;
            }
        }
        return;
    }
    // bid == 1484
    {
        float a1 = g1[t] * rsqrtf(v1[t] + 1e-3f);
        ab[t]       = a1 * 0.0625f;            // fold 1/16 weight scale
        ab[256 + t] = (b1[t] - m1[t]) * a1 + be1[t];
        float a2 = g2[t] * rsqrtf(v2[t] + 1e-3f);
        ab[512 + t] = a2 * 0.0625f;
        ab[768 + t] = (b2[t] - m2[t]) * a2 + be2[t];
        if (t < 192) ab[1024 + t] = (t < 130) ? b3[t] : 0.0f;
    }
}

// standalone geom (fallback path when y3 must live in d_out)
__global__ void geom_k(const float* __restrict__ rot, const float* __restrict__ trans,
                       const float* __restrict__ K, const float* __restrict__ prot,
                       const float* __restrict__ ptrans, float* __restrict__ out) {
    int idx = blockIdx.x * 256 + threadIdx.x;
    geom_point(idx, rot, trans, K, prot, ptrans, out);
}

// ---------------- conv 3x3 implicit GEMM, fp8 MFMA ----------------
// 256 threads / 4 waves, wave tile 32oc x 64px, double-buffered LDS,
// BAR6/BARL split barriers, setprio, XCD swizzle. fp8 e4m3: K-window = 128
// (18 windows), LDS rows 128B / 8 slots of 16B, XOR swizzle (conflict-free).
// Per window: 12 ds_read_b128 feed 32 MFMAs, 6 gld16 staged.
template<bool FP8OUT>
__global__ __launch_bounds__(256, 3) void conv8_mfma(
        const uint8_t* __restrict__ xin,  // fp8 padded NHWC-perm [6][34][90][256]
        const uint8_t* __restrict__ wp,   // fp8 [256][18][8][16]
        const float* __restrict__ ab, int abOff,
        uint8_t* __restrict__ yout8,      // fp8 out (conv1)
        f16* __restrict__ yout16)         // f16 out (conv2, linear channels)
{
    __shared__ alignas(16) uint8_t Ald[2][64 * 128];
    __shared__ alignas(16) uint8_t Bld[2][128 * 128];
    int t = threadIdx.x;
    int l = t & 63;
    int wid = t >> 6;
    // XCD-aware swizzle: 528 = 8 * 66, bijective.
    int bid = (blockIdx.x & 7) * 66 + (blockIdx.x >> 3);
    int bm = bid & 3;
    int bn = bid >> 2;
    int p0 = bn * 128;
    int wm = wid >> 1, wn = wid & 1;
    int swz = (l & 7) ^ (l >> 3);

    const uint8_t* asrc = wp + (size_t)(bm*64 + wid*16 + (l >> 3)) * 2304 + swz * 16;
    size_t bsrc[4];
    #pragma unroll
    for (int i = 0; i < 4; ++i) {
        int p = p0 + wid*32 + i*8 + (l >> 3);
        int n = p / 2816; int rem = p - n * 2816;
        int hh = rem / 88; int ww = rem - hh * 88;
        bsrc[i] = (size_t)((n*34 + hh) * 90 + ww) * 256 + swz * 16;
    }
    int aoff = wid * 2048 + l * 16;
    int boff = wid * 4096 + l * 16;

    floatx4 acc[2][4] = {};

    auto stage = [&](int win, uint8_t* Ab, uint8_t* Bb) {
        int tap = win >> 1;
        int koff = ((tap/3) * 90 + (tap%3)) * 256 + (win & 1) * 128;
        const uint8_t* aw = asrc + win * 128;
        gld16(aw,             Ab + aoff);
        gld16(aw + 8 * 2304,  Ab + aoff + 1024);
        #pragma unroll
        for (int j = 0; j < 4; ++j)
            gld16(xin + bsrc[j] + koff, Bb + boff + j * 1024);
    };
    auto compute = [&](const uint8_t* Ab, const uint8_t* Bb) {
        #pragma unroll
        for (int P = 0; P < 2; ++P) {
            i64x2 af[2], bf[4];
            int sl = (((P << 2) | (l >> 4)) ^ (l & 7)) * 16;
            #pragma unroll
            for (int m = 0; m < 2; ++m) {
                int row = wm*32 + m*16 + (l & 15);
                af[m] = *(const i64x2*)&Ab[row * 128 + sl];
            }
            #pragma unroll
            for (int n = 0; n < 4; ++n) {
                int row = wn*64 + n*16 + (l & 15);
                bf[n] = *(const i64x2*)&Bb[row * 128 + sl];
            }
            __builtin_amdgcn_s_setprio(1);
            #pragma unroll
            for (int m = 0; m < 2; ++m)
                #pragma unroll
                for (int n = 0; n < 4; ++n) {
                    acc[m][n] = __builtin_amdgcn_mfma_f32_16x16x32_fp8_fp8(af[m].x, bf[n].x, acc[m][n], 0, 0, 0);
                    acc[m][n] = __builtin_amdgcn_mfma_f32_16x16x32_fp8_fp8(af[m].y, bf[n].y, acc[m][n], 0, 0, 0);
                }
            __builtin_amdgcn_s_setprio(0);
        }
    };

    stage(0, Ald[0], Bld[0]);
    stage(1, Ald[1], Bld[1]);
    // steady state: 12 loads in flight; BAR6 retires the stage issued one
    // window ago while the newest 6 loads stay in flight across the barrier.
    #pragma unroll 1
    for (int win = 0; win < 16; win += 2) {
        PIPE_BAR6(); compute(Ald[0], Bld[0]);
        PIPE_BARL(); stage(win + 2, Ald[0], Bld[0]);
        PIPE_BAR6(); compute(Ald[1], Bld[1]);
        PIPE_BARL(); stage(win + 3, Ald[1], Bld[1]);
    }
    PIPE_BAR6(); compute(Ald[0], Bld[0]);   // win 16
    PIPE_BAR0(); compute(Ald[1], Bld[1]);   // win 17

    int ocb = bm*64 + wm*32;
    #pragma unroll
    for (int m = 0; m < 2; ++m) {
        int oc0 = ocb + m*16 + (l >> 4) * 4;
        float4 av = *(const float4*)&ab[abOff + oc0];
        float4 bv = *(const float4*)&ab[abOff + 256 + oc0];
        #pragma unroll
        for (int n = 0; n < 4; ++n) {
            int p = p0 + wn*64 + n*16 + (l & 15);
            int ni = p / 2816; int rem = p - ni * 2816;
            int hh = rem / 88; int ww = rem - hh * 88;
            size_t pxb = (size_t)((ni*34 + hh + 1) * 90 + (ww + 1)) * 256;
            float v0 = fmaxf(fmaf(acc[m][n][0], av.x, bv.x), 0.0f);
            float v1 = fmaxf(fmaf(acc[m][n][1], av.y, bv.y), 0.0f);
            float v2 = fmaxf(fmaf(acc[m][n][2], av.z, bv.z), 0.0f);
            float v3 = fmaxf(fmaf(acc[m][n][3], av.w, bv.w), 0.0f);
            if (FP8OUT) {
                *(uint32_t*)&yout8[pxb + fp8pos(oc0)] = pk4_fp8(v0, v1, v2, v3);
            } else {
                half4v hv;
                hv[0] = (f16)v0; hv[1] = (f16)v1; hv[2] = (f16)v2; hv[3] = (f16)v3;
                *(half4v*)&yout16[pxb + oc0] = hv;
            }
        }
    }
}

// ---------------- conv3 (1x1) MFMA GEMM f16, counted-vmcnt pipeline ----------------
__global__ __launch_bounds__(256) void conv3_mfma(
        const f16* __restrict__ xin,  // y2 padded NHWC f16 (linear channels)
        const f16* __restrict__ wp3,  // [192][256]
        const float* __restrict__ b3p,
        float* __restrict__ y3)       // [16896][132]
{
    __shared__ alignas(16) f16 Ald[3][64 * 64];
    __shared__ alignas(16) f16 Bld[3][128 * 64];
    int t = threadIdx.x;
    int l = t & 63;
    int wid = t >> 6;
    int bm = blockIdx.x % 3;
    int bn = blockIdx.x / 3;
    int p0 = bn * 128;
    int wm = wid >> 1, wn = wid & 1;
    int swz = (l & 7) ^ (l >> 3);

    const f16* asrc = wp3 + (size_t)(bm*64 + wid*16 + (l >> 3)) * 256 + swz * 8;
    size_t bsrc[4];
    #pragma unroll
    for (int i = 0; i < 4; ++i) {
        int p = p0 + wid*32 + i*8 + (l >> 3);
        int n = p / 2816; int rem = p - n * 2816;
        int hh = rem / 88; int ww = rem - hh * 88;
        bsrc[i] = (size_t)((n*34 + hh) * 90 + ww) * 256 + swz * 8;
    }
    int aoff = wid * 16 * 64;
    int boff = wid * 32 * 64;

    floatx4 acc[2][4] = {};

    auto stage = [&](int kt, f16* Ab, f16* Bb) {
        int koff = (1 * 90 + 1) * 256 + kt * 64;
        int k0 = kt * 64;
        gld16(asrc + k0,            Ab + aoff);
        gld16(asrc + k0 + 8 * 256,  Ab + aoff + 8 * 64);
        gld16(xin + bsrc[0] + koff, Bb + boff);
        gld16(xin + bsrc[1] + koff, Bb + boff + 8 * 64);
        gld16(xin + bsrc[2] + koff, Bb + boff + 16 * 64);
        gld16(xin + bsrc[3] + koff, Bb + boff + 24 * 64);
    };
    auto compute = [&](const f16* Ab, const f16* Bb) {
        #pragma unroll
        for (int kk = 0; kk < 2; ++kk) {
            half8 af[2], bf[4];
            int kslot = kk * 4 + (l >> 4);
            #pragma unroll
            for (int m = 0; m < 2; ++m) {
                int row = wm*32 + m*16 + (l & 15);
                af[m] = *(const half8*)&Ab[row * 64 + ((kslot ^ (row & 7)) * 8)];
            }
            #pragma unroll
            for (int n = 0; n < 4; ++n) {
                int row = wn*64 + n*16 + (l & 15);
                bf[n] = *(const half8*)&Bb[row * 64 + ((kslot ^ (row & 7)) * 8)];
            }
            __builtin_amdgcn_s_setprio(1);
            #pragma unroll
            for (int m = 0; m < 2; ++m)
                #pragma unroll
                for (int n = 0; n < 4; ++n)
                    acc[m][n] = __builtin_amdgcn_mfma_f32_16x16x32_f16(af[m], bf[n], acc[m][n], 0, 0, 0);
            __builtin_amdgcn_s_setprio(0);
        }
    };

    stage(0, Ald[0], Bld[0]);
    stage(1, Ald[1], Bld[1]);
    PIPE_BAR6(); stage(2, Ald[2], Bld[2]); compute(Ald[0], Bld[0]);  // kt=0
    PIPE_BAR6(); stage(3, Ald[0], Bld[0]); compute(Ald[1], Bld[1]);  // kt=1
    PIPE_BAR6(); compute(Ald[2], Bld[2]);                            // kt=2
    PIPE_BAR0(); compute(Ald[0], Bld[0]);                            // kt=3

    int ocb = bm*64 + wm*32;
    #pragma unroll
    for (int m = 0; m < 2; ++m) {
        int oc0 = ocb + m*16 + (l >> 4) * 4;
        if (oc0 < 132) {
            float4 bv = *(const float4*)&b3p[oc0];
            #pragma unroll
            for (int n = 0; n < 4; ++n) {
                int p = p0 + wn*64 + n*16 + (l & 15);
                float4 v;
                v.x = acc[m][n][0] + bv.x;
                v.y = acc[m][n][1] + bv.y;
                v.z = acc[m][n][2] + bv.z;
                v.w = acc[m][n][3] + bv.w;
                *(float4*)&y3[(size_t)p * 132 + oc0] = v;
            }
        }
    }
}

// ---------------- splat: gaussian expand + write (+ geom tail) ----------------
// Blocks 0..2111: 8 px/block (2 px per wave, 4 ch per lane): each wave stores
// 1024 B contiguous float4 per d-step, nontemporal. Gaussian normalization
// via LDS pre-pass. Blocks 2112+: geom (independent output; its VALU + 8.9 MB
// of writes hide inside the write-bound splat window).
__global__ __launch_bounds__(256) void splat_k(
        const float* __restrict__ y3, // [16896][132]: mu, ls, f0..f127
        const float* __restrict__ rot, const float* __restrict__ trans,
        const float* __restrict__ K, const float* __restrict__ prot,
        const float* __restrict__ ptrans,
        float* __restrict__ out)
{
    int t = threadIdx.x;
    int bid = blockIdx.x;
    if (bid >= 2112) {                 // geom tail
        int idx = (bid - 2112) * 256 + t;
        geom_point(idx, rot, trans, K, prot, ptrans, out);
        return;
    }

    __shared__ float eg[8][44];
    __shared__ float rs[8];
    int p0 = bid * 8;

    // pass 1: exp values for 8 px x 44 depths
    for (int i = t; i < 352; i += 256) {
        int px = i / 44, d = i - px * 44;
        const float* row = y3 + (size_t)(p0 + px) * 132;
        float mu = row[0];
        float sig = expf(row[1]) + 1e-6f;
        float z = (d + 1.0f) - mu;
        eg[px][d] = expf(-0.5f * z * z / (sig * sig));
    }
    __syncthreads();
    if (t < 8) {
        float s = 0.0f;
        for (int d = 0; d < 44; ++d) s += eg[t][d];
        rs[t] = 1.0f / (s + 1e-6f);
    }
    __syncthreads();

    int l = t & 63;
    int wid = t >> 6;
    int px = wid * 2 + (l >> 5);          // 0..7
    int ch = (l & 31) * 4;                // 0..124
    int p = p0 + px;
    int n = p / 2816; int rem = p - n * 2816;
    int h = rem / 88; int w = rem - h * 88;
    const float* row = y3 + (size_t)p * 132;
    floatx4 f4 = *(const floatx4*)&row[2 + ch];   // 8B-aligned dwordx4 (legal)
    float rsv = rs[px];

    size_t pxb = ((size_t)(n * 44) * 32 + h) * 88 + w;
    float* o1 = out + OUT1_OFF;
    #pragma unroll 4
    for (int d = 0; d < 44; ++d) {
        float gg = eg[px][d] * rsv;
        floatx4 v;
        v.x = gg * f4.x; v.y = gg * f4.y; v.z = gg * f4.z; v.w = gg * f4.w;
        __builtin_nontemporal_store(v, (floatx4*)&o1[(pxb + (size_t)d * 2816) * 128 + ch]);
    }
}

// ---------------- launch ----------------
extern "C" void kernel_launch(void* const* d_in, const int* in_sizes, int n_in,
                              void* d_out, int out_size, void* d_ws, size_t ws_size,
                              hipStream_t stream) {
    const float* rot    = (const float*)d_in[0];
    const float* trans  = (const float*)d_in[1];
    const float* K      = (const float*)d_in[2];
    const float* prot   = (const float*)d_in[3];
    const float* ptrans = (const float*)d_in[4];
    const float* feats  = (const float*)d_in[5];
    const float* w1     = (const float*)d_in[6];
    const float* b1     = (const float*)d_in[7];
    const float* g1     = (const float*)d_in[8];
    const float* be1    = (const float*)d_in[9];
    const float* m1     = (const float*)d_in[10];
    const float* v1     = (const float*)d_in[11];
    const float* w2     = (const float*)d_in[12];
    const float* b2     = (const float*)d_in[13];
    const float* g2     = (const float*)d_in[14];
    const float* be2    = (const float*)d_in[15];
    const float* m2     = (const float*)d_in[16];
    const float* v2     = (const float*)d_in[17];
    const float* w3     = (const float*)d_in[18];
    const float* b3     = (const float*)d_in[19];

    char* ws = (char*)d_ws;
    float*   ab    = (float*)(ws + AB_OFF);
    f16*     w3p   = (f16*)(ws + W3P_OFF);
    uint8_t* w1p8  = (uint8_t*)(ws + W1P_OFF);
    uint8_t* w2p8  = (uint8_t*)(ws + W2P_OFF);
    uint8_t* xpad8 = (uint8_t*)(ws + XPAD_OFF);
    uint8_t* y1p8  = (uint8_t*)(ws + Y1P8_OFF);
    f16*     y2    = (f16*)(ws + Y1P_OFF);
    float*   out   = (float*)d_out;

    bool y3InWs = ws_size >= (size_t)(Y3_WS_OFF + Y3_BYTES);
    float* y3 = y3InWs ? (float*)(ws + Y3_WS_OFF) : out;

    fused_prep<<<1485, 256, 0, stream>>>(
        feats, w1, w2, w3,
        b1, g1, be1, m1, v1, b2, g2, be2, m2, v2, b3,
        w1p8, w2p8, w3p, ab, xpad8, y1p8);
    conv8_mfma<true><<<528, 256, 0, stream>>>(xpad8, w1p8, ab, 0, y1p8, nullptr);
    conv8_mfma<false><<<528, 256, 0, stream>>>(y1p8, w2p8, ab, 512, nullptr, y2);
    conv3_mfma<<<396, 256, 0, stream>>>(y2, w3p, ab + 1024, y3);
    if (y3InWs) {
        // geom rides in the splat tail (write-bound window hides it)
        splat_k<<<2112 + 2904, 256, 0, stream>>>(y3, rot, trans, K, prot, ptrans, out);
    } else {
        splat_k<<<2112, 256, 0, stream>>>(y3, rot, trans, K, prot, ptrans, out);
        geom_k<<<2904, 256, 0, stream>>>(rot, trans, K, prot, ptrans, out);
    }
}